// Round 5
// baseline (268.950 us; speedup 1.0000x reference)
//
#include <hip/hip_runtime.h>
#include <hip/hip_bf16.h>

// SimVQ: z[16,1024,64] f32, codebook[16384,64] f32, proj_w[64,64] f32, proj_b[64] f32, scale f32
// Outputs (fp32, concat): quantized_st[1048576], vq_loss[1], idx[16384]
// r19: r18 REVERTED (stage-max reduce cost +30µs on pass1, pass2 skip gained ~0 -> proved
// pass time == staging skeleton, not payload: 695 TF == the known 2-phase plateau).
// New structure for both GEMM passes: NO LDS, NO barriers. g_cnb (2MB) is L2-resident per
// XCD; each wave streams its split's B fragments global->VGPR (de-swizzled addresses
// cnb[row][quad*8] / +32 == byte-identical data to the old LDS path -> bit-identical accs,
// margin proof intact). Wave owns 64 tokens (4 f-groups) halving B traffic vs 32:
// 2048 waves x 256KB = 512MB total = 64MB/XCD ~= 15µs L2 floor vs 14µs MFMA floor.
// Grid 512 blocks (64 tokGroups x 8 splits) = 2/CU, all resident, no tail.
// Margin scheme proven r5-r14: pass1 mfma top value, pass2 collect within 8e-3
// (bf16 quant err <= 4e-3 + Ozaki proj err ~1e-5), fp64 arbiter on cnt>=2 tokens.

#define NCODES 16384
#define NTOK   16384
#define DIM    64
#define MARGIN_MFMA 8e-3f
#define CAP    16

typedef __attribute__((ext_vector_type(8))) short bf16x8;
typedef __attribute__((ext_vector_type(4))) float f32x4;

__device__ float  g_qcb[NCODES * DIM];   // 4 MB projected codebook fp32 (gather source)
__device__ short  g_cnb[NCODES * DIM];   // 2 MB l2norm(qcb) bf16 row-major (MFMA B)
__device__ short  g_znb[NTOK * DIM];     // 2 MB l2norm(z)  bf16 row-major (MFMA A)
__device__ unsigned g_topu[NTOK];        // orderable-encoded mfma top-1 value
__device__ int    g_candcnt[NTOK];
__device__ int    g_cand[NTOK * CAP];    // 1 MB; slot 0 holds the winner after k_arb
__device__ int    g_wl[NTOK];            // flagged-token worklist
__device__ int    g_wln;
__device__ float  g_partial[512];        // per-block loss partials (all written every call)

__device__ __forceinline__ float wave_sum64(float v) {
#pragma unroll
  for (int o = 32; o > 0; o >>= 1) v += __shfl_xor(v, o, 64);
  return v;
}
__device__ __forceinline__ short f2bf(float f) {
  __hip_bfloat16 h = __float2bfloat16(f);
  return *reinterpret_cast<short*>(&h);
}
__device__ __forceinline__ float bf2f(short s) {
  __hip_bfloat16 h = *reinterpret_cast<__hip_bfloat16*>(&s);
  return __bfloat162float(h);
}
__device__ __forceinline__ void split8(const float* v, bf16x8& hi, bf16x8& lo) {
#pragma unroll
  for (int i = 0; i < 8; ++i) {
    float f = v[i];
    short h = f2bf(f);
    hi[i] = h;
    lo[i] = f2bf(f - bf2f(h));
  }
}

// k_prep: blocks [0,256): projection qc = cb@W^T + b via Ozaki hi/lo bf16 MFMA (fp32-class
// accuracy) -> fp32 qcb, bf16 cnb. blocks [256,512): znorm -> bf16 znb + zero per-call state.
__global__ __launch_bounds__(256) void k_prep(const float* __restrict__ cb,
                                              const float* __restrict__ pw,
                                              const float* __restrict__ pb,
                                              const float* __restrict__ z) {
  int tid = threadIdx.x;
  int wave = tid >> 6, lane = tid & 63, quad = lane >> 4, col = lane & 15;
  if (blockIdx.x < 256) {
    int rowBase = blockIdx.x * 64 + wave * 16;
    const float* cr = cb + (size_t)(rowBase + col) * 64 + quad * 8;
    bf16x8 ah0, al0, ah1, al1;
    split8(cr, ah0, al0);
    split8(cr + 32, ah1, al1);
    float vals[4][4];
    float nr[4] = {0.f, 0.f, 0.f, 0.f};
    const f32x4 fz = {0.f, 0.f, 0.f, 0.f};
#pragma unroll
    for (int nt = 0; nt < 4; ++nt) {
      int j = col + 16 * nt;
      const float* wr = pw + (size_t)j * 64 + quad * 8;
      bf16x8 bh0, bl0, bh1, bl1;
      split8(wr, bh0, bl0);
      split8(wr + 32, bh1, bl1);
      f32x4 d = __builtin_amdgcn_mfma_f32_16x16x32_bf16(ah0, bh0, fz, 0, 0, 0);
      d = __builtin_amdgcn_mfma_f32_16x16x32_bf16(ah1, bh1, d, 0, 0, 0);
      d = __builtin_amdgcn_mfma_f32_16x16x32_bf16(ah0, bl0, d, 0, 0, 0);
      d = __builtin_amdgcn_mfma_f32_16x16x32_bf16(ah1, bl1, d, 0, 0, 0);
      d = __builtin_amdgcn_mfma_f32_16x16x32_bf16(al0, bh0, d, 0, 0, 0);
      d = __builtin_amdgcn_mfma_f32_16x16x32_bf16(al1, bh1, d, 0, 0, 0);
      float bj = pb[j];
#pragma unroll
      for (int r = 0; r < 4; ++r) {
        float v = d[r] + bj;
        vals[nt][r] = v;
        nr[r] = fmaf(v, v, nr[r]);
      }
    }
#pragma unroll
    for (int r = 0; r < 4; ++r) {
      float v = nr[r];
      v += __shfl_xor(v, 1, 64);
      v += __shfl_xor(v, 2, 64);
      v += __shfl_xor(v, 4, 64);
      v += __shfl_xor(v, 8, 64);
      nr[r] = 1.0f / fmaxf(sqrtf(v), 1e-12f);
    }
#pragma unroll
    for (int nt = 0; nt < 4; ++nt)
#pragma unroll
      for (int r = 0; r < 4; ++r) {
        int row = rowBase + quad * 4 + r;
        int j = col + 16 * nt;
        g_qcb[(size_t)row * 64 + j] = vals[nt][r];
        g_cnb[(size_t)row * 64 + j] = f2bf(vals[nt][r] * nr[r]);
      }
  } else {
    int zb = blockIdx.x - 256;
    int gid = zb * 256 + tid;
    if (gid < NTOK) { g_topu[gid] = 0u; g_candcnt[gid] = 0; }
    if (gid == 0) g_wln = 0;
    int base = zb * 64;
    for (int r = 0; r < 16; ++r) {
      int row = base + wave * 16 + r;
      float v = z[(size_t)row * 64 + lane];
      float tot = wave_sum64(v * v);
      g_znb[(size_t)row * 64 + lane] = f2bf(v / fmaxf(sqrtf(tot), 1e-12f));
    }
  }
}

// GEMM pass 1 (r19): LDS-free streaming. Grid 512 = 64 tokGroups x 8 splits, 4 waves,
// wave owns 64 tokens (4 f-groups, A in 64 VGPR). Streams the split's 2048 codes in
// 16-code tiles: 2x global b128 per lane (coalesced 2KB/tile), 8 MFMA, 16 fmax. No
// barriers; compiler pipelines loads vs MFMA (unroll 4 -> 8 loads in flight).
__global__ __launch_bounds__(256) void k_mfma1() {
  int tid = threadIdx.x;
  int wave = tid >> 6, lane = tid & 63;
  int quad = lane >> 4, col = lane & 15;
  int tokGroup = blockIdx.x >> 3, split = blockIdx.x & 7;
  int tokBase = tokGroup * 256 + wave * 64;

  const short* za = g_znb + (size_t)(tokBase + col) * 64 + quad * 8;
  bf16x8 A0[4], A1[4];
#pragma unroll
  for (int f = 0; f < 4; ++f) {
    A0[f] = *(const bf16x8*)(za + f * 16 * 64);
    A1[f] = *(const bf16x8*)(za + f * 16 * 64 + 32);
  }
  float m[4][4];
#pragma unroll
  for (int f = 0; f < 4; ++f)
#pragma unroll
    for (int r = 0; r < 4; ++r) m[f][r] = -3.0e38f;

  // lane's B base: row = split*2048 + col, k-chunk quad*8 (b0) / +32 (b1)
  const short* bp = g_cnb + ((size_t)split * 2048 + col) * 64 + quad * 8;

#pragma unroll 4
  for (int t = 0; t < 128; ++t) {
    const short* pt = bp + t * 1024;  // +16 rows per tile
    bf16x8 b0 = *(const bf16x8*)(pt);
    bf16x8 b1 = *(const bf16x8*)(pt + 32);
#pragma unroll
    for (int f = 0; f < 4; ++f) {
      f32x4 acc = {0.f, 0.f, 0.f, 0.f};
      acc = __builtin_amdgcn_mfma_f32_16x16x32_bf16(A0[f], b0, acc, 0, 0, 0);
      acc = __builtin_amdgcn_mfma_f32_16x16x32_bf16(A1[f], b1, acc, 0, 0, 0);
#pragma unroll
      for (int r = 0; r < 4; ++r) m[f][r] = fmaxf(m[f][r], acc[r]);
    }
  }

#pragma unroll
  for (int f = 0; f < 4; ++f)
#pragma unroll
    for (int r = 0; r < 4; ++r) {
      float v = m[f][r];
      v = fmaxf(v, __shfl_xor(v, 1, 64));
      v = fmaxf(v, __shfl_xor(v, 2, 64));
      v = fmaxf(v, __shfl_xor(v, 4, 64));
      v = fmaxf(v, __shfl_xor(v, 8, 64));
      if (col == 0) {
        unsigned b = __float_as_uint(v);
        unsigned e = (b & 0x80000000u) ? ~b : (b | 0x80000000u);
        atomicMax(&g_topu[tokBase + f * 16 + quad * 4 + r], e);
      }
    }
}

// GEMM pass 2 (r19): same streaming skeleton; collect codes with acc >= top - margin.
__global__ __launch_bounds__(256) void k_mfma2() {
  int tid = threadIdx.x;
  int wave = tid >> 6, lane = tid & 63;
  int quad = lane >> 4, col = lane & 15;
  int tokGroup = blockIdx.x >> 3, split = blockIdx.x & 7;
  int tokBase = tokGroup * 256 + wave * 64;

  const short* za = g_znb + (size_t)(tokBase + col) * 64 + quad * 8;
  bf16x8 A0[4], A1[4];
#pragma unroll
  for (int f = 0; f < 4; ++f) {
    A0[f] = *(const bf16x8*)(za + f * 16 * 64);
    A1[f] = *(const bf16x8*)(za + f * 16 * 64 + 32);
  }
  float th[4][4];
#pragma unroll
  for (int f = 0; f < 4; ++f)
#pragma unroll
    for (int r = 0; r < 4; ++r) {
      unsigned u = g_topu[tokBase + f * 16 + quad * 4 + r];
      unsigned b = (u & 0x80000000u) ? (u & 0x7FFFFFFFu) : ~u;
      th[f][r] = __uint_as_float(b) - MARGIN_MFMA;
    }

  const short* bp = g_cnb + ((size_t)split * 2048 + col) * 64 + quad * 8;
  int codeB = split * 2048 + col;

#pragma unroll 4
  for (int t = 0; t < 128; ++t) {
    const short* pt = bp + t * 1024;
    bf16x8 b0 = *(const bf16x8*)(pt);
    bf16x8 b1 = *(const bf16x8*)(pt + 32);
    int code = codeB + t * 16;
#pragma unroll
    for (int f = 0; f < 4; ++f) {
      f32x4 acc = {0.f, 0.f, 0.f, 0.f};
      acc = __builtin_amdgcn_mfma_f32_16x16x32_bf16(A0[f], b0, acc, 0, 0, 0);
      acc = __builtin_amdgcn_mfma_f32_16x16x32_bf16(A1[f], b1, acc, 0, 0, 0);
      float dmax = fmaxf(fmaxf(acc[0] - th[f][0], acc[1] - th[f][1]),
                         fmaxf(acc[2] - th[f][2], acc[3] - th[f][3]));
      if (dmax >= 0.f) {
#pragma unroll
        for (int r = 0; r < 4; ++r) {
          if (acc[r] >= th[f][r]) {
            int tok = tokBase + f * 16 + quad * 4 + r;
            int pos = atomicAdd(&g_candcnt[tok], 1);
            if (pos < CAP) g_cand[tok * CAP + pos] = code;
          }
        }
      }
    }
  }
}

// k_scan: build worklist of flagged tokens (cnt >= 2). LDS flags + thread-0 serial
// exclusive scan (256 adds, trivial at 64 blocks) -> ONE atomicAdd per block.
__global__ __launch_bounds__(256) void k_scan() {
  __shared__ int flags[256];
  __shared__ int sbase;
  int tid = threadIdx.x;
  int tok = blockIdx.x * 256 + tid;
  int flag = (g_candcnt[tok] >= 2) ? 1 : 0;
  flags[tid] = flag;
  __syncthreads();
  if (tid == 0) {
    int run = 0;
    for (int i = 0; i < 256; ++i) {
      int f = flags[i];
      flags[i] = run;  // exclusive prefix
      run += f;
    }
    sbase = atomicAdd(&g_wln, run);
  }
  __syncthreads();
  if (flag) g_wl[sbase + flags[tid]] = tok;
}

// k_arb: resolve flagged tokens. 256 blocks x 4 waves = 1024 waves STRIDE the worklist
// (load-balanced, zero atomics). Per candidate: lane j computes qc_j = b_j + sum_k W[j,k]cb_k
// in fp64 via 4 independent chains (depth ~16 fma); WT layout [k][j] -> lane-stride-1 LDS
// reads (conflict-free). Score (z.qc)/||qc|| (monotone to ref), tie -> smallest code.
// Winner written to g_cand[tok*CAP]. Overflow (cnt>CAP): full fp64 scan (never fires).
__global__ __launch_bounds__(256) void k_arb(const float* __restrict__ z,
                                             const float* __restrict__ cb,
                                             const float* __restrict__ pw,
                                             const float* __restrict__ pb) {
  __shared__ double WT[64 * 65];  // WT[k*65+j] = W[j][k]
  __shared__ float cbl[4][64];
  int tid = threadIdx.x;
  int wave = tid >> 6, lane = tid & 63;
  for (int e = tid; e < 4096; e += 256) {
    int j = e >> 6, k = e & 63;
    WT[k * 65 + j] = (double)pw[e];
  }
  __syncthreads();

  int wln = g_wln;
  double bj = (double)pb[lane];
  int gwave = blockIdx.x * 4 + wave;

  for (int e = gwave; e < wln; e += 1024) {
    int tok = g_wl[e];
    int cnt = g_candcnt[tok];
    double zj = (double)z[(size_t)tok * 64 + lane];
    double best = -1.0e300;
    int bi = 0x7FFFFFFF;
    int lim = (cnt <= CAP) ? cnt : 0;
    for (int c = 0; c < lim; ++c) {
      int code = g_cand[tok * CAP + c];
      cbl[wave][lane] = cb[(size_t)code * 64 + lane];
      double s0 = 0.0, s1 = 0.0, s2 = 0.0, s3 = 0.0;
#pragma unroll
      for (int kk = 0; kk < 16; ++kk) {
        s0 = fma(WT[kk * 65 + lane], (double)cbl[wave][kk], s0);
        s1 = fma(WT[(kk + 16) * 65 + lane], (double)cbl[wave][kk + 16], s1);
        s2 = fma(WT[(kk + 32) * 65 + lane], (double)cbl[wave][kk + 32], s2);
        s3 = fma(WT[(kk + 48) * 65 + lane], (double)cbl[wave][kk + 48], s3);
      }
      double qc = ((s0 + s1) + (s2 + s3)) + bj;
      double s = zj * qc, n2 = qc * qc;
#pragma unroll
      for (int o = 32; o > 0; o >>= 1) {
        s += __shfl_xor(s, o, 64);
        n2 += __shfl_xor(n2, o, 64);
      }
      double key = s / fmax(sqrt(n2), 1e-12);
      if (key > best || (key == best && code < bi)) { best = key; bi = code; }
    }
    if (cnt > CAP) {  // correctness insurance; empirically never (max cnt seen <= 8 at r8)
      for (int code = 0; code < NCODES; ++code) {
        cbl[wave][lane] = cb[(size_t)code * 64 + lane];
        double s0 = 0.0, s1 = 0.0, s2 = 0.0, s3 = 0.0;
#pragma unroll
        for (int kk = 0; kk < 16; ++kk) {
          s0 = fma(WT[kk * 65 + lane], (double)cbl[wave][kk], s0);
          s1 = fma(WT[(kk + 16) * 65 + lane], (double)cbl[wave][kk + 16], s1);
          s2 = fma(WT[(kk + 32) * 65 + lane], (double)cbl[wave][kk + 32], s2);
          s3 = fma(WT[(kk + 48) * 65 + lane], (double)cbl[wave][kk + 48], s3);
        }
        double qc = ((s0 + s1) + (s2 + s3)) + bj;
        double s = zj * qc, n2 = qc * qc;
#pragma unroll
        for (int o = 32; o > 0; o >>= 1) {
          s += __shfl_xor(s, o, 64);
          n2 += __shfl_xor(n2, o, 64);
        }
        double key = s / fmax(sqrt(n2), 1e-12);
        if (key > best || (key == best && code < bi)) { best = key; bi = code; }
      }
    }
    if (lane == 0) g_cand[tok * CAP] = bi;
  }
}

// k_out: gather + straight-through + idx + per-block loss partial (plain stores only).
// 512 blocks x 32 tokens; wave handles 8 tokens.
__global__ __launch_bounds__(256) void k_out(const float* __restrict__ z,
                                             float* __restrict__ out0,
                                             float* __restrict__ out2) {
  __shared__ float ws[4];
  int tid = threadIdx.x;
  int wave = tid >> 6, lane = tid & 63;
  int base = blockIdx.x * 32;
  float lsum = 0.f;
  for (int r = 0; r < 8; ++r) {
    int tok = base + wave * 8 + r;
    int idx = g_cand[tok * CAP];  // winner (k_arb wrote it for flagged; slot0 otherwise)
    float q = g_qcb[(size_t)idx * 64 + lane];
    float zv = z[(size_t)tok * 64 + lane];
    float d = q - zv;
    out0[(size_t)tok * 64 + lane] = zv + d;  // z + (q - z), ref op order
    lsum = fmaf(d, d, lsum);
    if (lane == 0) out2[tok] = (float)idx;
  }
  float tot = wave_sum64(lsum);
  if (lane == 0) ws[wave] = tot;
  __syncthreads();
  if (tid == 0) g_partial[blockIdx.x] = ((ws[0] + ws[1]) + (ws[2] + ws[3]));
}

// k_loss: one wave sums the 512 partials in fixed order -> out1.
__global__ void k_loss(float* __restrict__ out1) {
  int lane = threadIdx.x;
  float s = 0.f;
#pragma unroll
  for (int i = 0; i < 8; ++i) s += g_partial[lane + 64 * i];
  s = wave_sum64(s);
  if (lane == 0) out1[0] = 1.25f * s / 1048576.0f;  // commitment == codebook numerically
}

extern "C" void kernel_launch(void* const* d_in, const int* in_sizes, int n_in,
                              void* d_out, int out_size, void* d_ws, size_t ws_size,
                              hipStream_t stream) {
  const float* z = (const float*)d_in[0];
  const float* cb = (const float*)d_in[1];
  const float* pw = (const float*)d_in[2];
  const float* pb = (const float*)d_in[3];
  // d_in[4] (scale) unused: argmin invariant to positive scale

  float* out0 = (float*)d_out;
  float* out1 = out0 + (size_t)NTOK * DIM;
  float* out2 = out1 + 1;

  hipLaunchKernelGGL(k_prep, dim3(512), dim3(256), 0, stream, cb, pw, pb, z);
  hipLaunchKernelGGL(k_mfma1, dim3(512), dim3(256), 0, stream);
  hipLaunchKernelGGL(k_mfma2, dim3(512), dim3(256), 0, stream);
  hipLaunchKernelGGL(k_scan, dim3(64), dim3(256), 0, stream);
  hipLaunchKernelGGL(k_arb, dim3(256), dim3(256), 0, stream, z, cb, pw, pb);
  hipLaunchKernelGGL(k_out, dim3(512), dim3(256), 0, stream, z, out0, out2);
  hipLaunchKernelGGL(k_loss, dim3(1), dim3(64), 0, stream, out1);
}

// Round 6
// 262.098 us; speedup vs baseline: 1.0261x; 1.0261x over previous
//
#include <hip/hip_runtime.h>
#include <hip/hip_bf16.h>

// SimVQ: z[16,1024,64] f32, codebook[16384,64] f32, proj_w[64,64] f32, proj_b[64] f32, scale f32
// Outputs (fp32, concat): quantized_st[1048576], vq_loss[1], idx[16384]
// r20: manual inline-asm software pipeline for the GEMM passes.
// Evidence chain: r16 LDS 2-phase = 49.5µs/pass (695 TF = known 2-phase plateau);
// r17 source reordering = null (compiler re-sinks); r18 payload-skip = null on pass2,
// regression on pass1; r19 compiler-scheduled global streaming = 85µs/pass (VGPR=48:
// loads serialized against MFMA). Conclusion: hipcc will not pipeline loads at source
// level. r20 takes ownership: asm volatile global_load_dwordx4 (no compiler waitcnt
// for asm loads), 4-tile register ring (static idx under full unroll), counted
// s_waitcnt vmcnt(6) + sched_barrier(0) gates (never vmcnt(0) in loop). Wave-private,
// no LDS, no barriers. 16 splits x 64 tokGroups = 1024 blocks (4/CU, 16 waves/CU).
// B addresses byte-identical to r19 (verified) -> bit-identical accs, margin proof holds.
// Margin scheme proven r5-r14: pass1 mfma top value, pass2 collect within 8e-3
// (bf16 quant err <= 4e-3 + Ozaki proj err ~1e-5), fp64 arbiter on cnt>=2 tokens.

#define NCODES 16384
#define NTOK   16384
#define DIM    64
#define MARGIN_MFMA 8e-3f
#define CAP    16

typedef __attribute__((ext_vector_type(8))) short bf16x8;
typedef __attribute__((ext_vector_type(4))) float f32x4;

__device__ float  g_qcb[NCODES * DIM];   // 4 MB projected codebook fp32 (gather source)
__device__ short  g_cnb[NCODES * DIM];   // 2 MB l2norm(qcb) bf16 row-major (MFMA B)
__device__ short  g_znb[NTOK * DIM];     // 2 MB l2norm(z)  bf16 row-major (MFMA A)
__device__ unsigned g_topu[NTOK];        // orderable-encoded mfma top-1 value
__device__ int    g_candcnt[NTOK];
__device__ int    g_cand[NTOK * CAP];    // 1 MB; slot 0 holds the winner after k_arb
__device__ int    g_wl[NTOK];            // flagged-token worklist
__device__ int    g_wln;
__device__ float  g_partial[512];        // per-block loss partials (all written every call)

__device__ __forceinline__ float wave_sum64(float v) {
#pragma unroll
  for (int o = 32; o > 0; o >>= 1) v += __shfl_xor(v, o, 64);
  return v;
}
__device__ __forceinline__ short f2bf(float f) {
  __hip_bfloat16 h = __float2bfloat16(f);
  return *reinterpret_cast<short*>(&h);
}
__device__ __forceinline__ float bf2f(short s) {
  __hip_bfloat16 h = *reinterpret_cast<__hip_bfloat16*>(&s);
  return __bfloat162float(h);
}
__device__ __forceinline__ void split8(const float* v, bf16x8& hi, bf16x8& lo) {
#pragma unroll
  for (int i = 0; i < 8; ++i) {
    float f = v[i];
    short h = f2bf(f);
    hi[i] = h;
    lo[i] = f2bf(f - bf2f(h));
  }
}

// async B-tile load: compiler inserts NO waitcnt for asm loads -> we own the pipeline.
__device__ __forceinline__ void gld_b128(bf16x8& dst, const short* addr) {
  asm volatile("global_load_dwordx4 %0, %1, off" : "=v"(dst) : "v"(addr));
}
// counted wait + scheduler fence (rule #18: sched_barrier right after the waitcnt so
// hipcc cannot hoist register-only MFMA above it).
#define WAITV(N)                                              \
  do {                                                        \
    asm volatile("s_waitcnt vmcnt(" #N ")" ::: "memory");     \
    __builtin_amdgcn_sched_barrier(0);                        \
  } while (0)

// k_prep: blocks [0,256): projection qc = cb@W^T + b via Ozaki hi/lo bf16 MFMA (fp32-class
// accuracy) -> fp32 qcb, bf16 cnb. blocks [256,512): znorm -> bf16 znb + zero per-call state.
__global__ __launch_bounds__(256) void k_prep(const float* __restrict__ cb,
                                              const float* __restrict__ pw,
                                              const float* __restrict__ pb,
                                              const float* __restrict__ z) {
  int tid = threadIdx.x;
  int wave = tid >> 6, lane = tid & 63, quad = lane >> 4, col = lane & 15;
  if (blockIdx.x < 256) {
    int rowBase = blockIdx.x * 64 + wave * 16;
    const float* cr = cb + (size_t)(rowBase + col) * 64 + quad * 8;
    bf16x8 ah0, al0, ah1, al1;
    split8(cr, ah0, al0);
    split8(cr + 32, ah1, al1);
    float vals[4][4];
    float nr[4] = {0.f, 0.f, 0.f, 0.f};
    const f32x4 fz = {0.f, 0.f, 0.f, 0.f};
#pragma unroll
    for (int nt = 0; nt < 4; ++nt) {
      int j = col + 16 * nt;
      const float* wr = pw + (size_t)j * 64 + quad * 8;
      bf16x8 bh0, bl0, bh1, bl1;
      split8(wr, bh0, bl0);
      split8(wr + 32, bh1, bl1);
      f32x4 d = __builtin_amdgcn_mfma_f32_16x16x32_bf16(ah0, bh0, fz, 0, 0, 0);
      d = __builtin_amdgcn_mfma_f32_16x16x32_bf16(ah1, bh1, d, 0, 0, 0);
      d = __builtin_amdgcn_mfma_f32_16x16x32_bf16(ah0, bl0, d, 0, 0, 0);
      d = __builtin_amdgcn_mfma_f32_16x16x32_bf16(ah1, bl1, d, 0, 0, 0);
      d = __builtin_amdgcn_mfma_f32_16x16x32_bf16(al0, bh0, d, 0, 0, 0);
      d = __builtin_amdgcn_mfma_f32_16x16x32_bf16(al1, bh1, d, 0, 0, 0);
      float bj = pb[j];
#pragma unroll
      for (int r = 0; r < 4; ++r) {
        float v = d[r] + bj;
        vals[nt][r] = v;
        nr[r] = fmaf(v, v, nr[r]);
      }
    }
#pragma unroll
    for (int r = 0; r < 4; ++r) {
      float v = nr[r];
      v += __shfl_xor(v, 1, 64);
      v += __shfl_xor(v, 2, 64);
      v += __shfl_xor(v, 4, 64);
      v += __shfl_xor(v, 8, 64);
      nr[r] = 1.0f / fmaxf(sqrtf(v), 1e-12f);
    }
#pragma unroll
    for (int nt = 0; nt < 4; ++nt)
#pragma unroll
      for (int r = 0; r < 4; ++r) {
        int row = rowBase + quad * 4 + r;
        int j = col + 16 * nt;
        g_qcb[(size_t)row * 64 + j] = vals[nt][r];
        g_cnb[(size_t)row * 64 + j] = f2bf(vals[nt][r] * nr[r]);
      }
  } else {
    int zb = blockIdx.x - 256;
    int gid = zb * 256 + tid;
    if (gid < NTOK) { g_topu[gid] = 0u; g_candcnt[gid] = 0; }
    if (gid == 0) g_wln = 0;
    int base = zb * 64;
    for (int r = 0; r < 16; ++r) {
      int row = base + wave * 16 + r;
      float v = z[(size_t)row * 64 + lane];
      float tot = wave_sum64(v * v);
      g_znb[(size_t)row * 64 + lane] = f2bf(v / fmaxf(sqrtf(tot), 1e-12f));
    }
  }
}

// GEMM pass 1 (r20): grid 1024 = 64 tokGroups x 16 splits, 4 waves/block, wave owns
// 64 tokens (A in 32 VGPR). Wave streams its split's 1024 codes as 64 16-code tiles
// through a 4-slot register ring: asm global_load_dwordx4 pairs, consume gated by
// vmcnt(6)+sched_barrier. No LDS, no barriers, steady-state 8 loads in flight.
__global__ __launch_bounds__(256, 4) void k_mfma1() {
  int tid = threadIdx.x;
  int wave = tid >> 6, lane = tid & 63;
  int quad = lane >> 4, col = lane & 15;
  int tokGroup = blockIdx.x >> 4, split = blockIdx.x & 15;
  int tokBase = tokGroup * 256 + wave * 64;

  const short* za = g_znb + (size_t)(tokBase + col) * 64 + quad * 8;
  bf16x8 A0[4], A1[4];
#pragma unroll
  for (int f = 0; f < 4; ++f) {
    A0[f] = *(const bf16x8*)(za + f * 16 * 64);
    A1[f] = *(const bf16x8*)(za + f * 16 * 64 + 32);
  }
  float m[4][4];
#pragma unroll
  for (int f = 0; f < 4; ++f)
#pragma unroll
    for (int r = 0; r < 4; ++r) m[f][r] = -3.0e38f;

  // lane's B base: row = split*1024 + col (+16/tile), k-chunk quad*8 (b0) / +32 (b1)
  const short* bp = g_cnb + ((size_t)split * 1024 + col) * 64 + quad * 8;

  bf16x8 B0[4], B1[4];
#pragma unroll
  for (int j = 0; j < 4; ++j) {
    gld_b128(B0[j], bp + (size_t)j * 1024);
    gld_b128(B1[j], bp + (size_t)j * 1024 + 32);
  }

  for (int tt = 0; tt < 15; ++tt) {
#pragma unroll
    for (int j = 0; j < 4; ++j) {
      int tile = tt * 4 + j;
      WAITV(6);
#pragma unroll
      for (int f = 0; f < 4; ++f) {
        f32x4 acc = {0.f, 0.f, 0.f, 0.f};
        acc = __builtin_amdgcn_mfma_f32_16x16x32_bf16(A0[f], B0[j], acc, 0, 0, 0);
        acc = __builtin_amdgcn_mfma_f32_16x16x32_bf16(A1[f], B1[j], acc, 0, 0, 0);
#pragma unroll
        for (int r = 0; r < 4; ++r) m[f][r] = fmaxf(m[f][r], acc[r]);
      }
      gld_b128(B0[j], bp + (size_t)(tile + 4) * 1024);
      gld_b128(B1[j], bp + (size_t)(tile + 4) * 1024 + 32);
    }
  }
  // epilogue tiles 60..63: no more issues, decreasing counted waits
#pragma unroll
  for (int j = 0; j < 4; ++j) {
    switch (j) {
      case 0: WAITV(6); break;
      case 1: WAITV(4); break;
      case 2: WAITV(2); break;
      default: WAITV(0); break;
    }
#pragma unroll
    for (int f = 0; f < 4; ++f) {
      f32x4 acc = {0.f, 0.f, 0.f, 0.f};
      acc = __builtin_amdgcn_mfma_f32_16x16x32_bf16(A0[f], B0[j], acc, 0, 0, 0);
      acc = __builtin_amdgcn_mfma_f32_16x16x32_bf16(A1[f], B1[j], acc, 0, 0, 0);
#pragma unroll
      for (int r = 0; r < 4; ++r) m[f][r] = fmaxf(m[f][r], acc[r]);
    }
  }

#pragma unroll
  for (int f = 0; f < 4; ++f)
#pragma unroll
    for (int r = 0; r < 4; ++r) {
      float v = m[f][r];
      v = fmaxf(v, __shfl_xor(v, 1, 64));
      v = fmaxf(v, __shfl_xor(v, 2, 64));
      v = fmaxf(v, __shfl_xor(v, 4, 64));
      v = fmaxf(v, __shfl_xor(v, 8, 64));
      if (col == 0) {
        unsigned b = __float_as_uint(v);
        unsigned e = (b & 0x80000000u) ? ~b : (b | 0x80000000u);
        atomicMax(&g_topu[tokBase + f * 16 + quad * 4 + r], e);
      }
    }
}

// GEMM pass 2 (r20): same ring skeleton; collect codes with acc >= top - margin.
// Rare atomic/store in consume only adds conservatism to vmcnt counting (issued after
// the waited-on loads).
__global__ __launch_bounds__(256, 4) void k_mfma2() {
  int tid = threadIdx.x;
  int wave = tid >> 6, lane = tid & 63;
  int quad = lane >> 4, col = lane & 15;
  int tokGroup = blockIdx.x >> 4, split = blockIdx.x & 15;
  int tokBase = tokGroup * 256 + wave * 64;

  const short* za = g_znb + (size_t)(tokBase + col) * 64 + quad * 8;
  bf16x8 A0[4], A1[4];
#pragma unroll
  for (int f = 0; f < 4; ++f) {
    A0[f] = *(const bf16x8*)(za + f * 16 * 64);
    A1[f] = *(const bf16x8*)(za + f * 16 * 64 + 32);
  }
  float th[4][4];
#pragma unroll
  for (int f = 0; f < 4; ++f)
#pragma unroll
    for (int r = 0; r < 4; ++r) {
      unsigned u = g_topu[tokBase + f * 16 + quad * 4 + r];
      unsigned b = (u & 0x80000000u) ? (u & 0x7FFFFFFFu) : ~u;
      th[f][r] = __uint_as_float(b) - MARGIN_MFMA;
    }

  const short* bp = g_cnb + ((size_t)split * 1024 + col) * 64 + quad * 8;
  int codeB = split * 1024 + col;

  bf16x8 B0[4], B1[4];
#pragma unroll
  for (int j = 0; j < 4; ++j) {
    gld_b128(B0[j], bp + (size_t)j * 1024);
    gld_b128(B1[j], bp + (size_t)j * 1024 + 32);
  }

  for (int tt = 0; tt < 15; ++tt) {
#pragma unroll
    for (int j = 0; j < 4; ++j) {
      int tile = tt * 4 + j;
      WAITV(6);
      int code = codeB + tile * 16;
#pragma unroll
      for (int f = 0; f < 4; ++f) {
        f32x4 acc = {0.f, 0.f, 0.f, 0.f};
        acc = __builtin_amdgcn_mfma_f32_16x16x32_bf16(A0[f], B0[j], acc, 0, 0, 0);
        acc = __builtin_amdgcn_mfma_f32_16x16x32_bf16(A1[f], B1[j], acc, 0, 0, 0);
        float dmax = fmaxf(fmaxf(acc[0] - th[f][0], acc[1] - th[f][1]),
                           fmaxf(acc[2] - th[f][2], acc[3] - th[f][3]));
        if (dmax >= 0.f) {
#pragma unroll
          for (int r = 0; r < 4; ++r) {
            if (acc[r] >= th[f][r]) {
              int tok = tokBase + f * 16 + quad * 4 + r;
              int pos = atomicAdd(&g_candcnt[tok], 1);
              if (pos < CAP) g_cand[tok * CAP + pos] = code;
            }
          }
        }
      }
      gld_b128(B0[j], bp + (size_t)(tile + 4) * 1024);
      gld_b128(B1[j], bp + (size_t)(tile + 4) * 1024 + 32);
    }
  }
#pragma unroll
  for (int j = 0; j < 4; ++j) {
    switch (j) {
      case 0: WAITV(6); break;
      case 1: WAITV(4); break;
      case 2: WAITV(2); break;
      default: WAITV(0); break;
    }
    int tile = 60 + j;
    int code = codeB + tile * 16;
#pragma unroll
    for (int f = 0; f < 4; ++f) {
      f32x4 acc = {0.f, 0.f, 0.f, 0.f};
      acc = __builtin_amdgcn_mfma_f32_16x16x32_bf16(A0[f], B0[j], acc, 0, 0, 0);
      acc = __builtin_amdgcn_mfma_f32_16x16x32_bf16(A1[f], B1[j], acc, 0, 0, 0);
      float dmax = fmaxf(fmaxf(acc[0] - th[f][0], acc[1] - th[f][1]),
                         fmaxf(acc[2] - th[f][2], acc[3] - th[f][3]));
      if (dmax >= 0.f) {
#pragma unroll
        for (int r = 0; r < 4; ++r) {
          if (acc[r] >= th[f][r]) {
            int tok = tokBase + f * 16 + quad * 4 + r;
            int pos = atomicAdd(&g_candcnt[tok], 1);
            if (pos < CAP) g_cand[tok * CAP + pos] = code;
          }
        }
      }
    }
  }
}

// k_scan: build worklist of flagged tokens (cnt >= 2). LDS flags + thread-0 serial
// exclusive scan (256 adds, trivial at 64 blocks) -> ONE atomicAdd per block.
__global__ __launch_bounds__(256) void k_scan() {
  __shared__ int flags[256];
  __shared__ int sbase;
  int tid = threadIdx.x;
  int tok = blockIdx.x * 256 + tid;
  int flag = (g_candcnt[tok] >= 2) ? 1 : 0;
  flags[tid] = flag;
  __syncthreads();
  if (tid == 0) {
    int run = 0;
    for (int i = 0; i < 256; ++i) {
      int f = flags[i];
      flags[i] = run;  // exclusive prefix
      run += f;
    }
    sbase = atomicAdd(&g_wln, run);
  }
  __syncthreads();
  if (flag) g_wl[sbase + flags[tid]] = tok;
}

// k_arb: resolve flagged tokens. 256 blocks x 4 waves = 1024 waves STRIDE the worklist
// (load-balanced, zero atomics). Per candidate: lane j computes qc_j = b_j + sum_k W[j,k]cb_k
// in fp64 via 4 independent chains (depth ~16 fma); WT layout [k][j] -> lane-stride-1 LDS
// reads (conflict-free). Score (z.qc)/||qc|| (monotone to ref), tie -> smallest code.
// Winner written to g_cand[tok*CAP]. Overflow (cnt>CAP): full fp64 scan (never fires).
__global__ __launch_bounds__(256) void k_arb(const float* __restrict__ z,
                                             const float* __restrict__ cb,
                                             const float* __restrict__ pw,
                                             const float* __restrict__ pb) {
  __shared__ double WT[64 * 65];  // WT[k*65+j] = W[j][k]
  __shared__ float cbl[4][64];
  int tid = threadIdx.x;
  int wave = tid >> 6, lane = tid & 63;
  for (int e = tid; e < 4096; e += 256) {
    int j = e >> 6, k = e & 63;
    WT[k * 65 + j] = (double)pw[e];
  }
  __syncthreads();

  int wln = g_wln;
  double bj = (double)pb[lane];
  int gwave = blockIdx.x * 4 + wave;

  for (int e = gwave; e < wln; e += 1024) {
    int tok = g_wl[e];
    int cnt = g_candcnt[tok];
    double zj = (double)z[(size_t)tok * 64 + lane];
    double best = -1.0e300;
    int bi = 0x7FFFFFFF;
    int lim = (cnt <= CAP) ? cnt : 0;
    for (int c = 0; c < lim; ++c) {
      int code = g_cand[tok * CAP + c];
      cbl[wave][lane] = cb[(size_t)code * 64 + lane];
      double s0 = 0.0, s1 = 0.0, s2 = 0.0, s3 = 0.0;
#pragma unroll
      for (int kk = 0; kk < 16; ++kk) {
        s0 = fma(WT[kk * 65 + lane], (double)cbl[wave][kk], s0);
        s1 = fma(WT[(kk + 16) * 65 + lane], (double)cbl[wave][kk + 16], s1);
        s2 = fma(WT[(kk + 32) * 65 + lane], (double)cbl[wave][kk + 32], s2);
        s3 = fma(WT[(kk + 48) * 65 + lane], (double)cbl[wave][kk + 48], s3);
      }
      double qc = ((s0 + s1) + (s2 + s3)) + bj;
      double s = zj * qc, n2 = qc * qc;
#pragma unroll
      for (int o = 32; o > 0; o >>= 1) {
        s += __shfl_xor(s, o, 64);
        n2 += __shfl_xor(n2, o, 64);
      }
      double key = s / fmax(sqrt(n2), 1e-12);
      if (key > best || (key == best && code < bi)) { best = key; bi = code; }
    }
    if (cnt > CAP) {  // correctness insurance; empirically never (max cnt seen <= 8 at r8)
      for (int code = 0; code < NCODES; ++code) {
        cbl[wave][lane] = cb[(size_t)code * 64 + lane];
        double s0 = 0.0, s1 = 0.0, s2 = 0.0, s3 = 0.0;
#pragma unroll
        for (int kk = 0; kk < 16; ++kk) {
          s0 = fma(WT[kk * 65 + lane], (double)cbl[wave][kk], s0);
          s1 = fma(WT[(kk + 16) * 65 + lane], (double)cbl[wave][kk + 16], s1);
          s2 = fma(WT[(kk + 32) * 65 + lane], (double)cbl[wave][kk + 32], s2);
          s3 = fma(WT[(kk + 48) * 65 + lane], (double)cbl[wave][kk + 48], s3);
        }
        double qc = ((s0 + s1) + (s2 + s3)) + bj;
        double s = zj * qc, n2 = qc * qc;
#pragma unroll
        for (int o = 32; o > 0; o >>= 1) {
          s += __shfl_xor(s, o, 64);
          n2 += __shfl_xor(n2, o, 64);
        }
        double key = s / fmax(sqrt(n2), 1e-12);
        if (key > best || (key == best && code < bi)) { best = key; bi = code; }
      }
    }
    if (lane == 0) g_cand[tok * CAP] = bi;
  }
}

// k_out: gather + straight-through + idx + per-block loss partial (plain stores only).
// 512 blocks x 32 tokens; wave handles 8 tokens.
__global__ __launch_bounds__(256) void k_out(const float* __restrict__ z,
                                             float* __restrict__ out0,
                                             float* __restrict__ out2) {
  __shared__ float ws[4];
  int tid = threadIdx.x;
  int wave = tid >> 6, lane = tid & 63;
  int base = blockIdx.x * 32;
  float lsum = 0.f;
  for (int r = 0; r < 8; ++r) {
    int tok = base + wave * 8 + r;
    int idx = g_cand[tok * CAP];  // winner (k_arb wrote it for flagged; slot0 otherwise)
    float q = g_qcb[(size_t)idx * 64 + lane];
    float zv = z[(size_t)tok * 64 + lane];
    float d = q - zv;
    out0[(size_t)tok * 64 + lane] = zv + d;  // z + (q - z), ref op order
    lsum = fmaf(d, d, lsum);
    if (lane == 0) out2[tok] = (float)idx;
  }
  float tot = wave_sum64(lsum);
  if (lane == 0) ws[wave] = tot;
  __syncthreads();
  if (tid == 0) g_partial[blockIdx.x] = ((ws[0] + ws[1]) + (ws[2] + ws[3]));
}

// k_loss: one wave sums the 512 partials in fixed order -> out1.
__global__ void k_loss(float* __restrict__ out1) {
  int lane = threadIdx.x;
  float s = 0.f;
#pragma unroll
  for (int i = 0; i < 8; ++i) s += g_partial[lane + 64 * i];
  s = wave_sum64(s);
  if (lane == 0) out1[0] = 1.25f * s / 1048576.0f;  // commitment == codebook numerically
}

extern "C" void kernel_launch(void* const* d_in, const int* in_sizes, int n_in,
                              void* d_out, int out_size, void* d_ws, size_t ws_size,
                              hipStream_t stream) {
  const float* z = (const float*)d_in[0];
  const float* cb = (const float*)d_in[1];
  const float* pw = (const float*)d_in[2];
  const float* pb = (const float*)d_in[3];
  // d_in[4] (scale) unused: argmin invariant to positive scale

  float* out0 = (float*)d_out;
  float* out1 = out0 + (size_t)NTOK * DIM;
  float* out2 = out1 + 1;

  hipLaunchKernelGGL(k_prep, dim3(512), dim3(256), 0, stream, cb, pw, pb, z);
  hipLaunchKernelGGL(k_mfma1, dim3(1024), dim3(256), 0, stream);
  hipLaunchKernelGGL(k_mfma2, dim3(1024), dim3(256), 0, stream);
  hipLaunchKernelGGL(k_scan, dim3(64), dim3(256), 0, stream);
  hipLaunchKernelGGL(k_arb, dim3(256), dim3(256), 0, stream, z, cb, pw, pb);
  hipLaunchKernelGGL(k_out, dim3(512), dim3(256), 0, stream, z, out0, out2);
  hipLaunchKernelGGL(k_loss, dim3(1), dim3(64), 0, stream, out1);
}

// Round 7
// 205.590 us; speedup vs baseline: 1.3082x; 1.2749x over previous
//
#include <hip/hip_runtime.h>
#include <hip/hip_bf16.h>

// SimVQ: z[16,1024,64] f32, codebook[16384,64] f32, proj_w[64,64] f32, proj_b[64] f32, scale f32
// Outputs (fp32, concat): quantized_st[1048576], vq_loss[1], idx[16384]
// r21 = r16's verified shared-LDS skeleton (best measured: 49.5µs/pass) + T4 counted-vmcnt
// ring pipeline. Structure scoreboard: LDS 2-phase 49.5 < reg-ring 75 (r20) < compiler
// streaming 85 (r19). r16's cost = per-stage __syncthreads vmcnt(0) drain (2-phase
// plateau). r21: 4-slot LDS ring (8KB/slot = 64 codes), stage loads issued 3 stages
// ahead via global_load_lds, gated by OWN-wave s_waitcnt vmcnt(4) BEFORE a raw s_barrier
// (no drain) -> 3 stages of loads stay in flight across barriers. Race-safety: ds_read
// results are consumed by pre-barrier MFMAs (compiler lgkmcnt), so slot reuse after the
// barrier cannot under-read; pass2 atomics only make counted waits conservative (vmcnt
// completes in order). Staging swizzle re-derived for 64-code stages: byte chunk x of
// code c stored at position x^(c&7); read offsets identical to r16's s0off/s1off ->
// byte-identical B rows -> bit-identical accs -> margin proof intact.
// Margin scheme proven r5-r14: pass1 mfma top value, pass2 collect within 8e-3
// (bf16 quant err <= 4e-3 + Ozaki proj err ~1e-5), fp64 arbiter on cnt>=2 tokens.

#define NCODES 16384
#define NTOK   16384
#define DIM    64
#define MARGIN_MFMA 8e-3f
#define CAP    16

typedef __attribute__((ext_vector_type(8))) short bf16x8;
typedef __attribute__((ext_vector_type(4))) float f32x4;
#define GLOBAL_AS __attribute__((address_space(1)))
#define LDS_AS    __attribute__((address_space(3)))

__device__ float  g_qcb[NCODES * DIM];   // 4 MB projected codebook fp32 (gather source)
__device__ short  g_cnb[NCODES * DIM];   // 2 MB l2norm(qcb) bf16 row-major (MFMA B)
__device__ short  g_znb[NTOK * DIM];     // 2 MB l2norm(z)  bf16 row-major (MFMA A)
__device__ unsigned g_topu[NTOK];        // orderable-encoded mfma top-1 value
__device__ int    g_candcnt[NTOK];
__device__ int    g_cand[NTOK * CAP];    // 1 MB; slot 0 holds the winner after k_arb
__device__ int    g_wl[NTOK];            // flagged-token worklist
__device__ int    g_wln;
__device__ float  g_partial[512];        // per-block loss partials (all written every call)

__device__ __forceinline__ float wave_sum64(float v) {
#pragma unroll
  for (int o = 32; o > 0; o >>= 1) v += __shfl_xor(v, o, 64);
  return v;
}
__device__ __forceinline__ short f2bf(float f) {
  __hip_bfloat16 h = __float2bfloat16(f);
  return *reinterpret_cast<short*>(&h);
}
__device__ __forceinline__ float bf2f(short s) {
  __hip_bfloat16 h = *reinterpret_cast<__hip_bfloat16*>(&s);
  return __bfloat162float(h);
}
__device__ __forceinline__ void split8(const float* v, bf16x8& hi, bf16x8& lo) {
#pragma unroll
  for (int i = 0; i < 8; ++i) {
    float f = v[i];
    short h = f2bf(f);
    hi[i] = h;
    lo[i] = f2bf(f - bf2f(h));
  }
}

// counted wait + scheduler fence (rule #18)
#define WAITV(N)                                              \
  do {                                                        \
    asm volatile("s_waitcnt vmcnt(" #N ")" ::: "memory");     \
    __builtin_amdgcn_sched_barrier(0);                        \
  } while (0)
#define RAW_BARRIER()                                         \
  do {                                                        \
    __builtin_amdgcn_s_barrier();                             \
    __builtin_amdgcn_sched_barrier(0);                        \
  } while (0)

// k_prep: blocks [0,256): projection qc = cb@W^T + b via Ozaki hi/lo bf16 MFMA (fp32-class
// accuracy) -> fp32 qcb, bf16 cnb. blocks [256,512): znorm -> bf16 znb + zero per-call state.
__global__ __launch_bounds__(256) void k_prep(const float* __restrict__ cb,
                                              const float* __restrict__ pw,
                                              const float* __restrict__ pb,
                                              const float* __restrict__ z) {
  int tid = threadIdx.x;
  int wave = tid >> 6, lane = tid & 63, quad = lane >> 4, col = lane & 15;
  if (blockIdx.x < 256) {
    int rowBase = blockIdx.x * 64 + wave * 16;
    const float* cr = cb + (size_t)(rowBase + col) * 64 + quad * 8;
    bf16x8 ah0, al0, ah1, al1;
    split8(cr, ah0, al0);
    split8(cr + 32, ah1, al1);
    float vals[4][4];
    float nr[4] = {0.f, 0.f, 0.f, 0.f};
    const f32x4 fz = {0.f, 0.f, 0.f, 0.f};
#pragma unroll
    for (int nt = 0; nt < 4; ++nt) {
      int j = col + 16 * nt;
      const float* wr = pw + (size_t)j * 64 + quad * 8;
      bf16x8 bh0, bl0, bh1, bl1;
      split8(wr, bh0, bl0);
      split8(wr + 32, bh1, bl1);
      f32x4 d = __builtin_amdgcn_mfma_f32_16x16x32_bf16(ah0, bh0, fz, 0, 0, 0);
      d = __builtin_amdgcn_mfma_f32_16x16x32_bf16(ah1, bh1, d, 0, 0, 0);
      d = __builtin_amdgcn_mfma_f32_16x16x32_bf16(ah0, bl0, d, 0, 0, 0);
      d = __builtin_amdgcn_mfma_f32_16x16x32_bf16(ah1, bl1, d, 0, 0, 0);
      d = __builtin_amdgcn_mfma_f32_16x16x32_bf16(al0, bh0, d, 0, 0, 0);
      d = __builtin_amdgcn_mfma_f32_16x16x32_bf16(al1, bh1, d, 0, 0, 0);
      float bj = pb[j];
#pragma unroll
      for (int r = 0; r < 4; ++r) {
        float v = d[r] + bj;
        vals[nt][r] = v;
        nr[r] = fmaf(v, v, nr[r]);
      }
    }
#pragma unroll
    for (int r = 0; r < 4; ++r) {
      float v = nr[r];
      v += __shfl_xor(v, 1, 64);
      v += __shfl_xor(v, 2, 64);
      v += __shfl_xor(v, 4, 64);
      v += __shfl_xor(v, 8, 64);
      nr[r] = 1.0f / fmaxf(sqrtf(v), 1e-12f);
    }
#pragma unroll
    for (int nt = 0; nt < 4; ++nt)
#pragma unroll
      for (int r = 0; r < 4; ++r) {
        int row = rowBase + quad * 4 + r;
        int j = col + 16 * nt;
        g_qcb[(size_t)row * 64 + j] = vals[nt][r];
        g_cnb[(size_t)row * 64 + j] = f2bf(vals[nt][r] * nr[r]);
      }
  } else {
    int zb = blockIdx.x - 256;
    int gid = zb * 256 + tid;
    if (gid < NTOK) { g_topu[gid] = 0u; g_candcnt[gid] = 0; }
    if (gid == 0) g_wln = 0;
    int base = zb * 64;
    for (int r = 0; r < 16; ++r) {
      int row = base + wave * 16 + r;
      float v = z[(size_t)row * 64 + lane];
      float tot = wave_sum64(v * v);
      g_znb[(size_t)row * 64 + lane] = f2bf(v / fmaxf(sqrtf(tot), 1e-12f));
    }
  }
}

// GEMM pass 1 (r21): grid 1024 = 128 tokBlocks x 8 splits, 4 waves/block, wave owns 32
// tokens. 4-slot LDS ring, 64 codes (8KB) per stage, 32 stages. Per stage per wave:
// 2x global_load_lds (1KB, pre-swizzled source), counted vmcnt(4) + raw s_barrier
// (3 stages of loads in flight), 8 ds_read_b128 + 16 MFMA consume.
__global__ __launch_bounds__(256) void k_mfma1() {
  __shared__ __align__(16) short smB[4][4096];
  int tid = threadIdx.x;
  int wave = tid >> 6, lane = tid & 63;
  int quad = lane >> 4, col = lane & 15;
  int tokBlock = blockIdx.x >> 3, split = blockIdx.x & 7;
  int tokBase = tokBlock * 128 + wave * 32;

  const short* za = g_znb + (size_t)(tokBase + col) * 64 + quad * 8;
  bf16x8 A0[2], A1[2];
#pragma unroll
  for (int f = 0; f < 2; ++f) {
    A0[f] = *(const bf16x8*)(za + f * 16 * 64);
    A1[f] = *(const bf16x8*)(za + f * 16 * 64 + 32);
  }
  float m[2][4];
#pragma unroll
  for (int f = 0; f < 2; ++f)
#pragma unroll
    for (int r = 0; r < 4; ++r) m[f][r] = -3.0e38f;

  const char* gsplit = (const char*)(g_cnb + (size_t)split * 2048 * 64);
  // pre-swizzled per-lane source: code chunk wave*16 + (lane>>3), byte chunk (lane&7)^(lane>>3)
  const char* srcBase = gsplit + (size_t)(wave * 16 + (lane >> 3)) * 128 +
                        (((lane & 7) ^ (lane >> 3)) << 4);
  int s0off = ((quad ^ (col & 7)) << 3);
  int s1off = (((4 | quad) ^ (col & 7)) << 3);

  // prologue: stages 0,1,2 (6 loads/wave in flight)
#pragma unroll
  for (int s = 0; s < 3; ++s)
#pragma unroll
    for (int i = 0; i < 2; ++i)
      __builtin_amdgcn_global_load_lds((const GLOBAL_AS void*)(srcBase + (size_t)s * 8192 + i * 1024),
                                       (LDS_AS void*)(&smB[s][wave * 1024 + i * 512]), 16, 0, 0);

#define M1_CONSUME(T)                                                              \
  {                                                                                \
    const short* bufp = smB[(T) & 3];                                              \
    _Pragma("unroll") for (int tt = 0; tt < 4; ++tt) {                             \
      const short* lb = bufp + (tt * 16 + col) * 64;                               \
      bf16x8 b0 = *(const bf16x8*)(lb + s0off);                                    \
      bf16x8 b1 = *(const bf16x8*)(lb + s1off);                                    \
      _Pragma("unroll") for (int f = 0; f < 2; ++f) {                              \
        f32x4 acc = {0.f, 0.f, 0.f, 0.f};                                          \
        acc = __builtin_amdgcn_mfma_f32_16x16x32_bf16(A0[f], b0, acc, 0, 0, 0);    \
        acc = __builtin_amdgcn_mfma_f32_16x16x32_bf16(A1[f], b1, acc, 0, 0, 0);    \
        _Pragma("unroll") for (int r = 0; r < 4; ++r)                              \
            m[f][r] = fmaxf(m[f][r], acc[r]);                                      \
      }                                                                            \
    }                                                                              \
  }

  for (int t = 0; t < 29; ++t) {
    WAITV(4);        // own stage-t loads complete (3 newer stages stay in flight)
    RAW_BARRIER();   // all waves' stage-t data resident; closes consumption of t-1
    int sl = (t + 3) & 3;
#pragma unroll
    for (int i = 0; i < 2; ++i)
      __builtin_amdgcn_global_load_lds((const GLOBAL_AS void*)(srcBase + (size_t)(t + 3) * 8192 + i * 1024),
                                       (LDS_AS void*)(&smB[sl][wave * 1024 + i * 512]), 16, 0, 0);
    M1_CONSUME(t);
  }
  WAITV(4); RAW_BARRIER(); M1_CONSUME(29);
  WAITV(2); RAW_BARRIER(); M1_CONSUME(30);
  WAITV(0); RAW_BARRIER(); M1_CONSUME(31);
#undef M1_CONSUME

#pragma unroll
  for (int f = 0; f < 2; ++f)
#pragma unroll
    for (int r = 0; r < 4; ++r) {
      float v = m[f][r];
      v = fmaxf(v, __shfl_xor(v, 1, 64));
      v = fmaxf(v, __shfl_xor(v, 2, 64));
      v = fmaxf(v, __shfl_xor(v, 4, 64));
      v = fmaxf(v, __shfl_xor(v, 8, 64));
      if (col == 0) {
        unsigned b = __float_as_uint(v);
        unsigned e = (b & 0x80000000u) ? ~b : (b | 0x80000000u);
        atomicMax(&g_topu[tokBase + f * 16 + quad * 4 + r], e);
      }
    }
}

// GEMM pass 2 (r21): same ring skeleton; collect codes with acc >= top - margin.
// Atomics/stores in consume only add conservatism to the counted waits (in-order vmcnt).
__global__ __launch_bounds__(256) void k_mfma2() {
  __shared__ __align__(16) short smB[4][4096];
  int tid = threadIdx.x;
  int wave = tid >> 6, lane = tid & 63;
  int quad = lane >> 4, col = lane & 15;
  int tokBlock = blockIdx.x >> 3, split = blockIdx.x & 7;
  int tokBase = tokBlock * 128 + wave * 32;

  const short* za = g_znb + (size_t)(tokBase + col) * 64 + quad * 8;
  bf16x8 A0[2], A1[2];
#pragma unroll
  for (int f = 0; f < 2; ++f) {
    A0[f] = *(const bf16x8*)(za + f * 16 * 64);
    A1[f] = *(const bf16x8*)(za + f * 16 * 64 + 32);
  }
  float th[2][4];
#pragma unroll
  for (int f = 0; f < 2; ++f)
#pragma unroll
    for (int r = 0; r < 4; ++r) {
      unsigned u = g_topu[tokBase + f * 16 + quad * 4 + r];
      unsigned b = (u & 0x80000000u) ? (u & 0x7FFFFFFFu) : ~u;
      th[f][r] = __uint_as_float(b) - MARGIN_MFMA;
    }

  const char* gsplit = (const char*)(g_cnb + (size_t)split * 2048 * 64);
  const char* srcBase = gsplit + (size_t)(wave * 16 + (lane >> 3)) * 128 +
                        (((lane & 7) ^ (lane >> 3)) << 4);
  int s0off = ((quad ^ (col & 7)) << 3);
  int s1off = (((4 | quad) ^ (col & 7)) << 3);
  int codeB = split * 2048 + col;

#pragma unroll
  for (int s = 0; s < 3; ++s)
#pragma unroll
    for (int i = 0; i < 2; ++i)
      __builtin_amdgcn_global_load_lds((const GLOBAL_AS void*)(srcBase + (size_t)s * 8192 + i * 1024),
                                       (LDS_AS void*)(&smB[s][wave * 1024 + i * 512]), 16, 0, 0);

#define M2_CONSUME(T)                                                              \
  {                                                                                \
    const short* bufp = smB[(T) & 3];                                              \
    _Pragma("unroll") for (int tt = 0; tt < 4; ++tt) {                             \
      const short* lb = bufp + (tt * 16 + col) * 64;                               \
      bf16x8 b0 = *(const bf16x8*)(lb + s0off);                                    \
      bf16x8 b1 = *(const bf16x8*)(lb + s1off);                                    \
      int code = codeB + (T) * 64 + tt * 16;                                       \
      _Pragma("unroll") for (int f = 0; f < 2; ++f) {                              \
        f32x4 acc = {0.f, 0.f, 0.f, 0.f};                                          \
        acc = __builtin_amdgcn_mfma_f32_16x16x32_bf16(A0[f], b0, acc, 0, 0, 0);    \
        acc = __builtin_amdgcn_mfma_f32_16x16x32_bf16(A1[f], b1, acc, 0, 0, 0);    \
        float dmax = fmaxf(fmaxf(acc[0] - th[f][0], acc[1] - th[f][1]),            \
                           fmaxf(acc[2] - th[f][2], acc[3] - th[f][3]));           \
        if (dmax >= 0.f) {                                                         \
          _Pragma("unroll") for (int r = 0; r < 4; ++r) {                          \
            if (acc[r] >= th[f][r]) {                                              \
              int tok = tokBase + f * 16 + quad * 4 + r;                           \
              int pos = atomicAdd(&g_candcnt[tok], 1);                             \
              if (pos < CAP) g_cand[tok * CAP + pos] = code;                       \
            }                                                                      \
          }                                                                        \
        }                                                                          \
      }                                                                            \
    }                                                                              \
  }

  for (int t = 0; t < 29; ++t) {
    WAITV(4);
    RAW_BARRIER();
    int sl = (t + 3) & 3;
#pragma unroll
    for (int i = 0; i < 2; ++i)
      __builtin_amdgcn_global_load_lds((const GLOBAL_AS void*)(srcBase + (size_t)(t + 3) * 8192 + i * 1024),
                                       (LDS_AS void*)(&smB[sl][wave * 1024 + i * 512]), 16, 0, 0);
    M2_CONSUME(t);
  }
  WAITV(4); RAW_BARRIER(); M2_CONSUME(29);
  WAITV(2); RAW_BARRIER(); M2_CONSUME(30);
  WAITV(0); RAW_BARRIER(); M2_CONSUME(31);
#undef M2_CONSUME
}

// k_scan: build worklist of flagged tokens (cnt >= 2). LDS flags + thread-0 serial
// exclusive scan (256 adds, trivial at 64 blocks) -> ONE atomicAdd per block.
__global__ __launch_bounds__(256) void k_scan() {
  __shared__ int flags[256];
  __shared__ int sbase;
  int tid = threadIdx.x;
  int tok = blockIdx.x * 256 + tid;
  int flag = (g_candcnt[tok] >= 2) ? 1 : 0;
  flags[tid] = flag;
  __syncthreads();
  if (tid == 0) {
    int run = 0;
    for (int i = 0; i < 256; ++i) {
      int f = flags[i];
      flags[i] = run;  // exclusive prefix
      run += f;
    }
    sbase = atomicAdd(&g_wln, run);
  }
  __syncthreads();
  if (flag) g_wl[sbase + flags[tid]] = tok;
}

// k_arb: resolve flagged tokens. 256 blocks x 4 waves = 1024 waves STRIDE the worklist
// (load-balanced, zero atomics). Per candidate: lane j computes qc_j = b_j + sum_k W[j,k]cb_k
// in fp64 via 4 independent chains (depth ~16 fma); WT layout [k][j] -> lane-stride-1 LDS
// reads (conflict-free). Score (z.qc)/||qc|| (monotone to ref), tie -> smallest code.
// Winner written to g_cand[tok*CAP]. Overflow (cnt>CAP): full fp64 scan (never fires).
__global__ __launch_bounds__(256) void k_arb(const float* __restrict__ z,
                                             const float* __restrict__ cb,
                                             const float* __restrict__ pw,
                                             const float* __restrict__ pb) {
  __shared__ double WT[64 * 65];  // WT[k*65+j] = W[j][k]
  __shared__ float cbl[4][64];
  int tid = threadIdx.x;
  int wave = tid >> 6, lane = tid & 63;
  for (int e = tid; e < 4096; e += 256) {
    int j = e >> 6, k = e & 63;
    WT[k * 65 + j] = (double)pw[e];
  }
  __syncthreads();

  int wln = g_wln;
  double bj = (double)pb[lane];
  int gwave = blockIdx.x * 4 + wave;

  for (int e = gwave; e < wln; e += 1024) {
    int tok = g_wl[e];
    int cnt = g_candcnt[tok];
    double zj = (double)z[(size_t)tok * 64 + lane];
    double best = -1.0e300;
    int bi = 0x7FFFFFFF;
    int lim = (cnt <= CAP) ? cnt : 0;
    for (int c = 0; c < lim; ++c) {
      int code = g_cand[tok * CAP + c];
      cbl[wave][lane] = cb[(size_t)code * 64 + lane];
      double s0 = 0.0, s1 = 0.0, s2 = 0.0, s3 = 0.0;
#pragma unroll
      for (int kk = 0; kk < 16; ++kk) {
        s0 = fma(WT[kk * 65 + lane], (double)cbl[wave][kk], s0);
        s1 = fma(WT[(kk + 16) * 65 + lane], (double)cbl[wave][kk + 16], s1);
        s2 = fma(WT[(kk + 32) * 65 + lane], (double)cbl[wave][kk + 32], s2);
        s3 = fma(WT[(kk + 48) * 65 + lane], (double)cbl[wave][kk + 48], s3);
      }
      double qc = ((s0 + s1) + (s2 + s3)) + bj;
      double s = zj * qc, n2 = qc * qc;
#pragma unroll
      for (int o = 32; o > 0; o >>= 1) {
        s += __shfl_xor(s, o, 64);
        n2 += __shfl_xor(n2, o, 64);
      }
      double key = s / fmax(sqrt(n2), 1e-12);
      if (key > best || (key == best && code < bi)) { best = key; bi = code; }
    }
    if (cnt > CAP) {  // correctness insurance; empirically never (max cnt seen <= 8 at r8)
      for (int code = 0; code < NCODES; ++code) {
        cbl[wave][lane] = cb[(size_t)code * 64 + lane];
        double s0 = 0.0, s1 = 0.0, s2 = 0.0, s3 = 0.0;
#pragma unroll
        for (int kk = 0; kk < 16; ++kk) {
          s0 = fma(WT[kk * 65 + lane], (double)cbl[wave][kk], s0);
          s1 = fma(WT[(kk + 16) * 65 + lane], (double)cbl[wave][kk + 16], s1);
          s2 = fma(WT[(kk + 32) * 65 + lane], (double)cbl[wave][kk + 32], s2);
          s3 = fma(WT[(kk + 48) * 65 + lane], (double)cbl[wave][kk + 48], s3);
        }
        double qc = ((s0 + s1) + (s2 + s3)) + bj;
        double s = zj * qc, n2 = qc * qc;
#pragma unroll
        for (int o = 32; o > 0; o >>= 1) {
          s += __shfl_xor(s, o, 64);
          n2 += __shfl_xor(n2, o, 64);
        }
        double key = s / fmax(sqrt(n2), 1e-12);
        if (key > best || (key == best && code < bi)) { best = key; bi = code; }
      }
    }
    if (lane == 0) g_cand[tok * CAP] = bi;
  }
}

// k_out: gather + straight-through + idx + per-block loss partial (plain stores only).
// 512 blocks x 32 tokens; wave handles 8 tokens.
__global__ __launch_bounds__(256) void k_out(const float* __restrict__ z,
                                             float* __restrict__ out0,
                                             float* __restrict__ out2) {
  __shared__ float ws[4];
  int tid = threadIdx.x;
  int wave = tid >> 6, lane = tid & 63;
  int base = blockIdx.x * 32;
  float lsum = 0.f;
  for (int r = 0; r < 8; ++r) {
    int tok = base + wave * 8 + r;
    int idx = g_cand[tok * CAP];  // winner (k_arb wrote it for flagged; slot0 otherwise)
    float q = g_qcb[(size_t)idx * 64 + lane];
    float zv = z[(size_t)tok * 64 + lane];
    float d = q - zv;
    out0[(size_t)tok * 64 + lane] = zv + d;  // z + (q - z), ref op order
    lsum = fmaf(d, d, lsum);
    if (lane == 0) out2[tok] = (float)idx;
  }
  float tot = wave_sum64(lsum);
  if (lane == 0) ws[wave] = tot;
  __syncthreads();
  if (tid == 0) g_partial[blockIdx.x] = ((ws[0] + ws[1]) + (ws[2] + ws[3]));
}

// k_loss: one wave sums the 512 partials in fixed order -> out1.
__global__ void k_loss(float* __restrict__ out1) {
  int lane = threadIdx.x;
  float s = 0.f;
#pragma unroll
  for (int i = 0; i < 8; ++i) s += g_partial[lane + 64 * i];
  s = wave_sum64(s);
  if (lane == 0) out1[0] = 1.25f * s / 1048576.0f;  // commitment == codebook numerically
}

extern "C" void kernel_launch(void* const* d_in, const int* in_sizes, int n_in,
                              void* d_out, int out_size, void* d_ws, size_t ws_size,
                              hipStream_t stream) {
  const float* z = (const float*)d_in[0];
  const float* cb = (const float*)d_in[1];
  const float* pw = (const float*)d_in[2];
  const float* pb = (const float*)d_in[3];
  // d_in[4] (scale) unused: argmin invariant to positive scale

  float* out0 = (float*)d_out;
  float* out1 = out0 + (size_t)NTOK * DIM;
  float* out2 = out1 + 1;

  hipLaunchKernelGGL(k_prep, dim3(512), dim3(256), 0, stream, cb, pw, pb, z);
  hipLaunchKernelGGL(k_mfma1, dim3(1024), dim3(256), 0, stream);
  hipLaunchKernelGGL(k_mfma2, dim3(1024), dim3(256), 0, stream);
  hipLaunchKernelGGL(k_scan, dim3(64), dim3(256), 0, stream);
  hipLaunchKernelGGL(k_arb, dim3(256), dim3(256), 0, stream, z, cb, pw, pb);
  hipLaunchKernelGGL(k_out, dim3(512), dim3(256), 0, stream, z, out0, out2);
  hipLaunchKernelGGL(k_loss, dim3(1), dim3(64), 0, stream, out1);
}